// Round 8
// baseline (435.805 us; speedup 1.0000x reference)
//
#include <hip/hip_runtime.h>
#include <hip/hip_bf16.h>

#define NN 50000
#define NE 800000

typedef unsigned int u32;
typedef unsigned short u16;
typedef __attribute__((ext_vector_type(2))) _Float16 half2v;
typedef __attribute__((ext_vector_type(8))) _Float16 half8;
typedef __attribute__((ext_vector_type(4))) float f32x4;    // MFMA C/D

__device__ __forceinline__ float silu_f(float x) {
    return x * (1.0f / (1.0f + __expf(-x)));
}
__device__ __forceinline__ u16 f2h_bits(float f) {          // f32 -> f16 (HW RNE)
    union { _Float16 h; u16 u; } c; c.h = (_Float16)f; return c.u;
}
__device__ __forceinline__ _Float16 h_from_bits(u16 u) {
    union { u16 u; _Float16 h; } c; c.u = u; return c.h;
}
__device__ __forceinline__ float h2f(u16 u) {
    return (float)h_from_bits(u);
}

// ---------------------------------------------------------------------------
// Sort-by-DST machinery: histogram -> 2-level exclusive scan -> scatter ranks
// ---------------------------------------------------------------------------
__global__ __launch_bounds__(256) void k_hist(const int* __restrict__ ei, u32* __restrict__ cnt) {
    int e = blockIdx.x * 256 + threadIdx.x;
    atomicAdd(&cnt[ei[NE + e]], 1u);
}

__global__ __launch_bounds__(256) void k_scan_a(const u32* __restrict__ cnt, u32* __restrict__ part) {
    __shared__ u32 sb[256];
    int t = threadIdx.x, i = blockIdx.x * 256 + t;
    u32 v = (i < NN) ? cnt[i] : 0u;
    sb[t] = v; __syncthreads();
    for (int off = 128; off > 0; off >>= 1) { if (t < off) sb[t] += sb[t + off]; __syncthreads(); }
    if (t == 0) part[blockIdx.x] = sb[0];
}

__global__ __launch_bounds__(256) void k_scan_b(u32* __restrict__ part, int nparts) {
    __shared__ u32 sb[256];
    int t = threadIdx.x;
    u32 v = (t < nparts) ? part[t] : 0u;
    sb[t] = v; __syncthreads();
    for (int off = 1; off < 256; off <<= 1) {
        u32 x = (t >= off) ? sb[t - off] : 0u; __syncthreads();
        sb[t] += x; __syncthreads();
    }
    if (t < nparts) part[t] = sb[t] - v;          // exclusive
}

__global__ __launch_bounds__(256) void k_scan_c(const u32* __restrict__ cnt, const u32* __restrict__ part,
                                                u32* __restrict__ row, u32* __restrict__ rowcur) {
    __shared__ u32 sb[256];
    int t = threadIdx.x, i = blockIdx.x * 256 + t;
    u32 v = (i < NN) ? cnt[i] : 0u;
    sb[t] = v; __syncthreads();
    for (int off = 1; off < 256; off <<= 1) {
        u32 x = (t >= off) ? sb[t - off] : 0u; __syncthreads();
        sb[t] += x; __syncthreads();
    }
    if (i < NN) {
        u32 ex = part[blockIdx.x] + sb[t] - v;
        row[i] = ex; rowcur[i] = ex;
    }
    if (i == 0) row[NN] = NE;
}

__global__ __launch_bounds__(256) void k_scatter(const int* __restrict__ ei, u32* __restrict__ rowcur,
                                                 u32* __restrict__ rank, u32* __restrict__ ssrc,
                                                 u16* __restrict__ sdst) {
    int e = blockIdx.x * 256 + threadIdx.x;
    u32 s_ = (u32)ei[e];
    u32 d_ = (u32)ei[NE + e];
    u32 pos = atomicAdd(&rowcur[d_], 1u);
    rank[e] = pos;
    ssrc[pos] = s_;
    sdst[pos] = (u16)d_;
}

// ---------------------------------------------------------------------------
// Wt transpose: WtT[g][m*64+f] = f16(W_tp[f][m][g])   [64][576] f16
// ---------------------------------------------------------------------------
__global__ __launch_bounds__(256) void k_wt(const float* __restrict__ Wtp, u16* __restrict__ WtT) {
    int o = blockIdx.x * 256 + threadIdx.x;     // 0..36863
    int g = o / 576, k = o % 576;
    int m = k >> 6, f = k & 63;
    WtT[o] = f2h_bits(Wtp[f * 576 + m * 64 + g]);
}

// ---------------------------------------------------------------------------
// K1: per-edge weight MLP; writes s (f16, padded to 12) at dst-sorted pos.
// ---------------------------------------------------------------------------
__global__ __launch_bounds__(256) void k_edge_mlp(
    const float* __restrict__ edge_attr, const float* __restrict__ edge_sh,
    const float* __restrict__ W1, const float* __restrict__ b1,
    const float* __restrict__ W2, const float* __restrict__ b2,
    const u32* __restrict__ rank,
    u16* __restrict__ s_sorted)            // [NE][12] f16 at rank[e]
{
    __shared__ float sAttr[256 * 36];
    const int t  = threadIdx.x;
    const int e0 = blockIdx.x * 256;

    const float* ga = edge_attr + (size_t)e0 * 32;
    #pragma unroll
    for (int k = 0; k < 32; ++k) {
        int i = k * 256 + t;
        sAttr[(i >> 5) * 36 + (i & 31)] = ga[i];
    }
    __syncthreads();

    float a[32];
    #pragma unroll
    for (int q = 0; q < 8; ++q) {
        float4 v = *(const float4*)&sAttr[t * 36 + q * 4];
        a[4*q+0] = v.x; a[4*q+1] = v.y; a[4*q+2] = v.z; a[4*q+3] = v.w;
    }

    float hid[64];
    #pragma unroll
    for (int h = 0; h < 64; ++h) hid[h] = b1[h];
    for (int d = 0; d < 32; ++d) {
        const float ad = a[d];
        const float* wr = W1 + d * 64;
        #pragma unroll
        for (int h = 0; h < 64; ++h) hid[h] += ad * wr[h];
    }

    float w[9];
    #pragma unroll
    for (int m = 0; m < 9; ++m) w[m] = b2[m];
    for (int h = 0; h < 64; ++h) {
        const float hv = silu_f(hid[h]);
        const float* w2r = W2 + h * 9;
        #pragma unroll
        for (int m = 0; m < 9; ++m) w[m] += hv * w2r[m];
    }

    const size_t e = (size_t)e0 + t;
    const float* sh = edge_sh + e * 9;
    u16 sw[12];
    #pragma unroll
    for (int m = 0; m < 9; ++m) sw[m] = f2h_bits(sh[m] * w[m]);
    sw[9] = sw[10] = sw[11] = 0;

    u16* dp = s_sorted + (size_t)rank[e] * 12;
    ushort4 v0{sw[0], sw[1], sw[2],  sw[3]};
    ushort4 v1{sw[4], sw[5], sw[6],  sw[7]};
    ushort4 v2{sw[8], sw[9], sw[10], sw[11]};
    *(ushort4*)(dp + 0) = v0;
    *(ushort4*)(dp + 4) = v1;
    *(ushort4*)(dp + 8) = v2;
}

// ---------------------------------------------------------------------------
// K3: MFMA combine, f16 datapath.  Block = 256 dst-sorted edges, 4 waves.
// A-frag = (h f16) * (s f16) via v_pk_mul_f16 — 4 pk-muls per 4 MFMAs.
// C tiles -> LDS msg[256][68] f16 (34.8 KB => 4 blocks/CU) -> segmented
// per-node reduce -> ~17 atomics/block.
// ---------------------------------------------------------------------------
__global__ __launch_bounds__(256, 4) void k_combine_mfma(
    const u32* __restrict__ ssrc, const u16* __restrict__ sdst,
    const u32* __restrict__ row,  const u16* __restrict__ s_sorted,
    const float* __restrict__ feat, const u16* __restrict__ WtT,
    float* __restrict__ out)
{
    __shared__ u16 msg[256 * 68];          // f16 bits
    const int t  = threadIdx.x;
    const int w  = t >> 6;
    const int l  = t & 63;
    const int p0 = blockIdx.x * 256;
    const int rbase = w << 6;

    // this lane's A-row edge for each et-tile
    u32 srcr[4];
    half2v s2[4][9];                        // {s,s} pairs
    #pragma unroll
    for (int et = 0; et < 4; ++et) {
        const int p = p0 + rbase + (et << 4) + (l & 15);
        srcr[et] = ssrc[p];
        const u16* sp = s_sorted + (size_t)p * 12;
        #pragma unroll
        for (int m = 0; m < 9; ++m) {
            _Float16 sv = h_from_bits(sp[m]);
            s2[et][m] = half2v{sv, sv};
        }
    }

    f32x4 acc[4][4] = {};
    #pragma unroll
    for (int fhalf = 0; fhalf < 2; ++fhalf) {
        // h slice -> f16 pairs (8 values per et), converted once
        half2v h16[4][4];
        #pragma unroll
        for (int et = 0; et < 4; ++et) {
            const float* hp = feat + (size_t)srcr[et] * 64 + (fhalf << 5) + ((l >> 4) << 3);
            float4 v0 = *(const float4*)hp;
            float4 v1 = *(const float4*)(hp + 4);
            h16[et][0] = half2v{(_Float16)v0.x, (_Float16)v0.y};
            h16[et][1] = half2v{(_Float16)v0.z, (_Float16)v0.w};
            h16[et][2] = half2v{(_Float16)v1.x, (_Float16)v1.y};
            h16[et][3] = half2v{(_Float16)v1.z, (_Float16)v1.w};
        }
        #pragma unroll
        for (int m = 0; m < 9; ++m) {
            const int tt = (m << 1) + fhalf;          // K-slice: k = tt*32 ..
            half8 bfr[4];
            #pragma unroll
            for (int gt = 0; gt < 4; ++gt)
                bfr[gt] = *(const half8*)(WtT +
                    (size_t)(((gt << 4) + (l & 15)) * 576 + tt * 32 + ((l >> 4) << 3)));
            #pragma unroll
            for (int et = 0; et < 4; ++et) {
                union { half2v h2[4]; half8 v; } A;
                A.h2[0] = h16[et][0] * s2[et][m];      // v_pk_mul_f16
                A.h2[1] = h16[et][1] * s2[et][m];
                A.h2[2] = h16[et][2] * s2[et][m];
                A.h2[3] = h16[et][3] * s2[et][m];
                #pragma unroll
                for (int gt = 0; gt < 4; ++gt)
                    acc[et][gt] = __builtin_amdgcn_mfma_f32_16x16x32_f16(A.v, bfr[gt], acc[et][gt], 0, 0, 0);
            }
        }
    }

    // ---- C tiles -> LDS msg[256][68] f16 (disjoint cells) ----
    #pragma unroll
    for (int et = 0; et < 4; ++et)
        #pragma unroll
        for (int gt = 0; gt < 4; ++gt)
            #pragma unroll
            for (int rg = 0; rg < 4; ++rg) {
                int rloc = rbase + (et << 4) + ((l >> 4) << 2) + rg;   // C row = edge
                int col  = (gt << 4) + (l & 15);                       // C col = g
                msg[rloc * 68 + col] = f2h_bits(acc[et][gt][rg]);
            }
    __syncthreads();

    // ---- segmented per-node reduction; one atomic per (node,g) per block ----
    const int dfirst = sdst[p0];
    const int dlast  = sdst[p0 + 255];
    for (int n = dfirst + w; n <= dlast; n += 4) {
        int a = (int)row[n]     - p0; if (a < 0)   a = 0;
        int b = (int)row[n + 1] - p0; if (b > 256) b = 256;
        if (a < b) {
            float v = 0.f;
            for (int p = a; p < b; ++p) v += h2f(msg[p * 68 + l]);
            atomicAdd(out + (size_t)n * 64 + l, v * 0.25f);    // 1/sqrt(16)
        }
    }
}

// ---------------------------------------------------------------------------
// K4: FiLM, in-place on d_out.
// ---------------------------------------------------------------------------
__global__ __launch_bounds__(256) void k_film(
    const float* __restrict__ c_noise,
    const float* __restrict__ Wn1, const float* __restrict__ bn1,
    const float* __restrict__ Wn2, const float* __restrict__ bn2,
    float* __restrict__ out)
{
    const int n    = (blockIdx.x * 256 + threadIdx.x) >> 6;
    const int lane = threadIdx.x & 63;
    const float c  = c_noise[n];
    const float hid = silu_f(fmaf(c, Wn1[lane], bn1[lane]));
    float g = bn2[lane], b = bn2[64 + lane];
    for (int h = 0; h < 64; ++h) {
        const float hv = __shfl(hid, h, 64);
        g = fmaf(hv, Wn2[h * 128 + lane],      g);
        b = fmaf(hv, Wn2[h * 128 + 64 + lane], b);
    }
    const size_t i = (size_t)n * 64 + lane;
    out[i] = fmaf(out[i], 1.f + g, b);
}

// ---------------------------------------------------------------------------
extern "C" void kernel_launch(void* const* d_in, const int* in_sizes, int n_in,
                              void* d_out, int out_size, void* d_ws, size_t ws_size,
                              hipStream_t stream) {
    const float* features   = (const float*)d_in[0];
    const int*   edge_index = (const int*)  d_in[1];
    const float* edge_attr  = (const float*)d_in[2];
    const float* edge_sh    = (const float*)d_in[3];
    const float* c_noise    = (const float*)d_in[4];
    const float* W1  = (const float*)d_in[5];
    const float* b1  = (const float*)d_in[6];
    const float* W2  = (const float*)d_in[7];
    const float* b2  = (const float*)d_in[8];
    const float* Wtp = (const float*)d_in[9];
    const float* Wn1 = (const float*)d_in[10];
    const float* bn1 = (const float*)d_in[11];
    const float* Wn2 = (const float*)d_in[12];
    const float* bn2 = (const float*)d_in[13];
    float* out = (float*)d_out;

    char* ws = (char*)d_ws;
    u16* s_sorted = (u16*)(ws);                    // 19,200,000 B
    u32* ssrc     = (u32*)(ws + 19200000);         //  3,200,000 B
    u32* rank     = (u32*)(ws + 22400000);         //  3,200,000 B
    u16* sdst     = (u16*)(ws + 25600000);         //  1,600,000 B
    u32* row      = (u32*)(ws + 27200000);         //    200,016 B (NN+1)
    u32* rowcur   = (u32*)(ws + 27400016);         //    200,000 B
    u32* cnt      = (u32*)(ws + 27600016);         //    200,000 B
    u32* part     = (u32*)(ws + 27800016);         //      1,024 B
    u16* WtT      = (u16*)(ws + 27801040);         //     73,728 B  (end ~27.9 MB)

    const int nparts = (NN + 255) / 256;           // 196

    hipMemsetAsync(cnt, 0, (size_t)NN * 4, stream);
    hipMemsetAsync(out, 0, (size_t)NN * 64 * sizeof(float), stream);

    k_hist   <<<NE / 256, 256, 0, stream>>>(edge_index, cnt);
    k_scan_a <<<nparts, 256, 0, stream>>>(cnt, part);
    k_scan_b <<<1, 256, 0, stream>>>(part, nparts);
    k_scan_c <<<nparts, 256, 0, stream>>>(cnt, part, row, rowcur);
    k_scatter<<<NE / 256, 256, 0, stream>>>(edge_index, rowcur, rank, ssrc, sdst);

    k_wt      <<<(576 * 64) / 256, 256, 0, stream>>>(Wtp, WtT);
    k_edge_mlp<<<NE / 256, 256, 0, stream>>>(edge_attr, edge_sh, W1, b1, W2, b2, rank, s_sorted);

    k_combine_mfma<<<NE / 256, 256, 0, stream>>>(ssrc, sdst, row, s_sorted,
                                                 features, WtT, out);

    k_film<<<(NN * 64) / 256, 256, 0, stream>>>(c_noise, Wn1, bn1, Wn2, bn2, out);
}

// Round 9
// 390.564 us; speedup vs baseline: 1.1158x; 1.1158x over previous
//
#include <hip/hip_runtime.h>
#include <hip/hip_bf16.h>

#define NN 50000
#define NE 800000

typedef unsigned int u32;
typedef unsigned short u16;
typedef __attribute__((ext_vector_type(2))) _Float16 half2v;
typedef __attribute__((ext_vector_type(8))) _Float16 half8;
typedef __attribute__((ext_vector_type(4))) float f32x4;    // MFMA C/D

__device__ __forceinline__ float silu_f(float x) {
    return x * (1.0f / (1.0f + __expf(-x)));
}
__device__ __forceinline__ u16 f2h_bits(float f) {          // f32 -> f16 (HW RNE)
    union { _Float16 h; u16 u; } c; c.h = (_Float16)f; return c.u;
}
__device__ __forceinline__ _Float16 h_from_bits(u16 u) {
    union { u16 u; _Float16 h; } c; c.u = u; return c.h;
}
__device__ __forceinline__ float h2f(u16 u) {
    return (float)h_from_bits(u);
}

// ---------------------------------------------------------------------------
// Sort-by-DST machinery: histogram -> 2-level exclusive scan -> scatter ranks
// ---------------------------------------------------------------------------
__global__ __launch_bounds__(256) void k_hist(const int* __restrict__ ei, u32* __restrict__ cnt) {
    int e = blockIdx.x * 256 + threadIdx.x;
    atomicAdd(&cnt[ei[NE + e]], 1u);
}

__global__ __launch_bounds__(256) void k_scan_a(const u32* __restrict__ cnt, u32* __restrict__ part) {
    __shared__ u32 sb[256];
    int t = threadIdx.x, i = blockIdx.x * 256 + t;
    u32 v = (i < NN) ? cnt[i] : 0u;
    sb[t] = v; __syncthreads();
    for (int off = 128; off > 0; off >>= 1) { if (t < off) sb[t] += sb[t + off]; __syncthreads(); }
    if (t == 0) part[blockIdx.x] = sb[0];
}

__global__ __launch_bounds__(256) void k_scan_b(u32* __restrict__ part, int nparts) {
    __shared__ u32 sb[256];
    int t = threadIdx.x;
    u32 v = (t < nparts) ? part[t] : 0u;
    sb[t] = v; __syncthreads();
    for (int off = 1; off < 256; off <<= 1) {
        u32 x = (t >= off) ? sb[t - off] : 0u; __syncthreads();
        sb[t] += x; __syncthreads();
    }
    if (t < nparts) part[t] = sb[t] - v;          // exclusive
}

__global__ __launch_bounds__(256) void k_scan_c(const u32* __restrict__ cnt, const u32* __restrict__ part,
                                                u32* __restrict__ row, u32* __restrict__ rowcur) {
    __shared__ u32 sb[256];
    int t = threadIdx.x, i = blockIdx.x * 256 + t;
    u32 v = (i < NN) ? cnt[i] : 0u;
    sb[t] = v; __syncthreads();
    for (int off = 1; off < 256; off <<= 1) {
        u32 x = (t >= off) ? sb[t - off] : 0u; __syncthreads();
        sb[t] += x; __syncthreads();
    }
    if (i < NN) {
        u32 ex = part[blockIdx.x] + sb[t] - v;
        row[i] = ex; rowcur[i] = ex;
    }
    if (i == 0) row[NN] = NE;
}

__global__ __launch_bounds__(256) void k_scatter(const int* __restrict__ ei, u32* __restrict__ rowcur,
                                                 u32* __restrict__ rank, u32* __restrict__ ssrc,
                                                 u16* __restrict__ sdst) {
    int e = blockIdx.x * 256 + threadIdx.x;
    u32 s_ = (u32)ei[e];
    u32 d_ = (u32)ei[NE + e];
    u32 pos = atomicAdd(&rowcur[d_], 1u);
    rank[e] = pos;
    ssrc[pos] = s_;
    sdst[pos] = (u16)d_;
}

// ---------------------------------------------------------------------------
// feat f32 -> f16 copy: feat16[n][f] (6.4 MB, near-L2-resident working set)
// ---------------------------------------------------------------------------
__global__ __launch_bounds__(256) void k_feat16(const float* __restrict__ feat, u16* __restrict__ feat16) {
    int i = blockIdx.x * 256 + threadIdx.x;      // 400000 threads, 8 elems each
    const float* fp = feat + (size_t)i * 8;
    float4 v0 = *(const float4*)fp;
    float4 v1 = *(const float4*)(fp + 4);
    ushort4 o0{f2h_bits(v0.x), f2h_bits(v0.y), f2h_bits(v0.z), f2h_bits(v0.w)};
    ushort4 o1{f2h_bits(v1.x), f2h_bits(v1.y), f2h_bits(v1.z), f2h_bits(v1.w)};
    u16* op = feat16 + (size_t)i * 8;
    *(ushort4*)op = o0;
    *(ushort4*)(op + 4) = o1;
}

// ---------------------------------------------------------------------------
// Wt transpose: WtT[g][m*64+f] = f16(W_tp[f][m][g])   [64][576] f16
// ---------------------------------------------------------------------------
__global__ __launch_bounds__(256) void k_wt(const float* __restrict__ Wtp, u16* __restrict__ WtT) {
    int o = blockIdx.x * 256 + threadIdx.x;     // 0..36863
    int g = o / 576, k = o % 576;
    int m = k >> 6, f = k & 63;
    WtT[o] = f2h_bits(Wtp[f * 576 + m * 64 + g]);
}

// ---------------------------------------------------------------------------
// K1: per-edge weight MLP; writes s (f16, padded to 12) at dst-sorted pos.
// ---------------------------------------------------------------------------
__global__ __launch_bounds__(256) void k_edge_mlp(
    const float* __restrict__ edge_attr, const float* __restrict__ edge_sh,
    const float* __restrict__ W1, const float* __restrict__ b1,
    const float* __restrict__ W2, const float* __restrict__ b2,
    const u32* __restrict__ rank,
    u16* __restrict__ s_sorted)            // [NE][12] f16 at rank[e]
{
    __shared__ float sAttr[256 * 36];
    const int t  = threadIdx.x;
    const int e0 = blockIdx.x * 256;

    const float* ga = edge_attr + (size_t)e0 * 32;
    #pragma unroll
    for (int k = 0; k < 32; ++k) {
        int i = k * 256 + t;
        sAttr[(i >> 5) * 36 + (i & 31)] = ga[i];
    }
    __syncthreads();

    float a[32];
    #pragma unroll
    for (int q = 0; q < 8; ++q) {
        float4 v = *(const float4*)&sAttr[t * 36 + q * 4];
        a[4*q+0] = v.x; a[4*q+1] = v.y; a[4*q+2] = v.z; a[4*q+3] = v.w;
    }

    float hid[64];
    #pragma unroll
    for (int h = 0; h < 64; ++h) hid[h] = b1[h];
    for (int d = 0; d < 32; ++d) {
        const float ad = a[d];
        const float* wr = W1 + d * 64;
        #pragma unroll
        for (int h = 0; h < 64; ++h) hid[h] += ad * wr[h];
    }

    float w[9];
    #pragma unroll
    for (int m = 0; m < 9; ++m) w[m] = b2[m];
    for (int h = 0; h < 64; ++h) {
        const float hv = silu_f(hid[h]);
        const float* w2r = W2 + h * 9;
        #pragma unroll
        for (int m = 0; m < 9; ++m) w[m] += hv * w2r[m];
    }

    const size_t e = (size_t)e0 + t;
    const float* sh = edge_sh + e * 9;
    u16 sw[12];
    #pragma unroll
    for (int m = 0; m < 9; ++m) sw[m] = f2h_bits(sh[m] * w[m]);
    sw[9] = sw[10] = sw[11] = 0;

    u16* dp = s_sorted + (size_t)rank[e] * 12;
    ushort4 v0{sw[0], sw[1], sw[2],  sw[3]};
    ushort4 v1{sw[4], sw[5], sw[6],  sw[7]};
    ushort4 v2{sw[8], sw[9], sw[10], sw[11]};
    *(ushort4*)(dp + 0) = v0;
    *(ushort4*)(dp + 4) = v1;
    *(ushort4*)(dp + 8) = v2;
}

// ---------------------------------------------------------------------------
// K3: MFMA combine, f16 datapath, f16 feat gather (128 B/edge), hoisted loads.
// Block = 256 dst-sorted edges, 4 waves.  A-frag = h16 * s via v_pk_mul_f16.
// C tiles -> LDS msg[256][68] f16 -> segmented reduce; interior nodes use
// plain stores (all their edges are in-block), only boundary nodes atomic.
// ---------------------------------------------------------------------------
__global__ __launch_bounds__(256, 4) void k_combine_mfma(
    const u32* __restrict__ ssrc, const u16* __restrict__ sdst,
    const u32* __restrict__ row,  const u16* __restrict__ s_sorted,
    const u16* __restrict__ feat16, const u16* __restrict__ WtT,
    float* __restrict__ out)
{
    __shared__ u16 msg[256 * 68];          // f16 bits
    const int t  = threadIdx.x;
    const int w  = t >> 6;
    const int l  = t & 63;
    const int p0 = blockIdx.x * 256;
    const int rbase = w << 6;

    // ---- hoisted: srcs, then 8 independent 16B feat gathers, then s ----
    u32 srcr[4];
    #pragma unroll
    for (int et = 0; et < 4; ++et)
        srcr[et] = ssrc[p0 + rbase + (et << 4) + (l & 15)];

    half8 h16[4][2];                        // [et][fhalf]
    #pragma unroll
    for (int et = 0; et < 4; ++et)
        #pragma unroll
        for (int fh = 0; fh < 2; ++fh)
            h16[et][fh] = *(const half8*)(feat16 +
                (size_t)srcr[et] * 64 + (fh << 5) + ((l >> 4) << 3));

    half2v s2[4][9];                        // {s,s} pairs
    #pragma unroll
    for (int et = 0; et < 4; ++et) {
        const u16* sp = s_sorted + (size_t)(p0 + rbase + (et << 4) + (l & 15)) * 12;
        #pragma unroll
        for (int m = 0; m < 9; ++m) {
            _Float16 sv = h_from_bits(sp[m]);
            s2[et][m] = half2v{sv, sv};
        }
    }

    f32x4 acc[4][4] = {};
    #pragma unroll
    for (int fhalf = 0; fhalf < 2; ++fhalf) {
        #pragma unroll
        for (int m = 0; m < 9; ++m) {
            const int tt = (m << 1) + fhalf;          // K-slice: k = tt*32 ..
            half8 bfr[4];
            #pragma unroll
            for (int gt = 0; gt < 4; ++gt)
                bfr[gt] = *(const half8*)(WtT +
                    (size_t)(((gt << 4) + (l & 15)) * 576 + tt * 32 + ((l >> 4) << 3)));
            #pragma unroll
            for (int et = 0; et < 4; ++et) {
                union { half2v h2[4]; half8 v; } A;
                const union { half8 v; half2v h2[4]; } H = { h16[et][fhalf] };
                A.h2[0] = H.h2[0] * s2[et][m];         // v_pk_mul_f16
                A.h2[1] = H.h2[1] * s2[et][m];
                A.h2[2] = H.h2[2] * s2[et][m];
                A.h2[3] = H.h2[3] * s2[et][m];
                #pragma unroll
                for (int gt = 0; gt < 4; ++gt)
                    acc[et][gt] = __builtin_amdgcn_mfma_f32_16x16x32_f16(A.v, bfr[gt], acc[et][gt], 0, 0, 0);
            }
        }
    }

    // ---- C tiles -> LDS msg[256][68] f16 (disjoint cells) ----
    #pragma unroll
    for (int et = 0; et < 4; ++et)
        #pragma unroll
        for (int gt = 0; gt < 4; ++gt)
            #pragma unroll
            for (int rg = 0; rg < 4; ++rg) {
                int rloc = rbase + (et << 4) + ((l >> 4) << 2) + rg;   // C row = edge
                int col  = (gt << 4) + (l & 15);                       // C col = g
                msg[rloc * 68 + col] = f2h_bits(acc[et][gt][rg]);
            }
    __syncthreads();

    // ---- segmented per-node reduction ----
    const int dfirst = sdst[p0];
    const int dlast  = sdst[p0 + 255];
    for (int n = dfirst + w; n <= dlast; n += 4) {
        int a = (int)row[n]     - p0; if (a < 0)   a = 0;
        int b = (int)row[n + 1] - p0; if (b > 256) b = 256;
        if (a < b) {
            float v = 0.f;
            for (int p = a; p < b; ++p) v += h2f(msg[p * 68 + l]);
            v *= 0.25f;                                    // 1/sqrt(16)
            float* op = out + (size_t)n * 64 + l;
            if (n == dfirst || n == dlast) atomicAdd(op, v);   // may span blocks
            else                           *op = v;            // fully in-block
        }
    }
}

// ---------------------------------------------------------------------------
// K4: FiLM, in-place on d_out.
// ---------------------------------------------------------------------------
__global__ __launch_bounds__(256) void k_film(
    const float* __restrict__ c_noise,
    const float* __restrict__ Wn1, const float* __restrict__ bn1,
    const float* __restrict__ Wn2, const float* __restrict__ bn2,
    float* __restrict__ out)
{
    const int n    = (blockIdx.x * 256 + threadIdx.x) >> 6;
    const int lane = threadIdx.x & 63;
    const float c  = c_noise[n];
    const float hid = silu_f(fmaf(c, Wn1[lane], bn1[lane]));
    float g = bn2[lane], b = bn2[64 + lane];
    for (int h = 0; h < 64; ++h) {
        const float hv = __shfl(hid, h, 64);
        g = fmaf(hv, Wn2[h * 128 + lane],      g);
        b = fmaf(hv, Wn2[h * 128 + 64 + lane], b);
    }
    const size_t i = (size_t)n * 64 + lane;
    out[i] = fmaf(out[i], 1.f + g, b);
}

// ---------------------------------------------------------------------------
extern "C" void kernel_launch(void* const* d_in, const int* in_sizes, int n_in,
                              void* d_out, int out_size, void* d_ws, size_t ws_size,
                              hipStream_t stream) {
    const float* features   = (const float*)d_in[0];
    const int*   edge_index = (const int*)  d_in[1];
    const float* edge_attr  = (const float*)d_in[2];
    const float* edge_sh    = (const float*)d_in[3];
    const float* c_noise    = (const float*)d_in[4];
    const float* W1  = (const float*)d_in[5];
    const float* b1  = (const float*)d_in[6];
    const float* W2  = (const float*)d_in[7];
    const float* b2  = (const float*)d_in[8];
    const float* Wtp = (const float*)d_in[9];
    const float* Wn1 = (const float*)d_in[10];
    const float* bn1 = (const float*)d_in[11];
    const float* Wn2 = (const float*)d_in[12];
    const float* bn2 = (const float*)d_in[13];
    float* out = (float*)d_out;

    char* ws = (char*)d_ws;
    u16* feat16   = (u16*)(ws);                    //  6,400,000 B
    u16* s_sorted = (u16*)(ws +  6400000);         // 19,200,000 B
    u32* ssrc     = (u32*)(ws + 25600000);         //  3,200,000 B
    u32* rank     = (u32*)(ws + 28800000);         //  3,200,000 B
    u16* sdst     = (u16*)(ws + 32000000);         //  1,600,000 B
    u32* row      = (u32*)(ws + 33600000);         //    200,016 B (NN+1)
    u32* rowcur   = (u32*)(ws + 33800016);         //    200,000 B
    u32* cnt      = (u32*)(ws + 34000016);         //    200,000 B
    u32* part     = (u32*)(ws + 34200016);         //      1,024 B
    u16* WtT      = (u16*)(ws + 34201040);         //     73,728 B  (end ~34.3 MB)

    const int nparts = (NN + 255) / 256;           // 196

    hipMemsetAsync(cnt, 0, (size_t)NN * 4, stream);
    hipMemsetAsync(out, 0, (size_t)NN * 64 * sizeof(float), stream);

    k_hist   <<<NE / 256, 256, 0, stream>>>(edge_index, cnt);
    k_scan_a <<<nparts, 256, 0, stream>>>(cnt, part);
    k_scan_b <<<1, 256, 0, stream>>>(part, nparts);
    k_scan_c <<<nparts, 256, 0, stream>>>(cnt, part, row, rowcur);
    k_scatter<<<NE / 256, 256, 0, stream>>>(edge_index, rowcur, rank, ssrc, sdst);

    k_feat16  <<<(NN * 64 / 8 + 255) / 256, 256, 0, stream>>>(features, feat16);
    k_wt      <<<(576 * 64) / 256, 256, 0, stream>>>(Wtp, WtT);
    k_edge_mlp<<<NE / 256, 256, 0, stream>>>(edge_attr, edge_sh, W1, b1, W2, b2, rank, s_sorted);

    k_combine_mfma<<<NE / 256, 256, 0, stream>>>(ssrc, sdst, row, s_sorted,
                                                 feat16, WtT, out);

    k_film<<<(NN * 64) / 256, 256, 0, stream>>>(c_noise, Wn1, bn1, Wn2, bn2, out);
}